// Round 6
// baseline (1572.543 us; speedup 1.0000x reference)
//
#include <hip/hip_runtime.h>
#include <math.h>
#include <float.h>

#define M_TOK   32768
#define NSYM    8192
#define KDIM    1024
#define LAT     512

#define DECAY_F 0.995f
#define OMD_F   0.005f
#define GBS_F   0.7f
#define EPS_F   1e-6f
#define WIN_F   3.0f            // 0.7 bias + 2*(6-sigma bf16 screen err) + margin

typedef unsigned short u16;
typedef unsigned int   u32;
typedef short short8 __attribute__((ext_vector_type(8)));
typedef float f32x4  __attribute__((ext_vector_type(4)));

#define GLOAD_LDS16(g, l) \
    __builtin_amdgcn_global_load_lds((const __attribute__((address_space(1))) u32*)(g), \
                                     (__attribute__((address_space(3))) u32*)(l), 16, 0, 0)

__device__ __forceinline__ u16 f2bf(float f) {
    u32 u = __float_as_uint(f);
    return (u16)((u + 0x7FFF + ((u >> 16) & 1)) >> 16);   // round-to-nearest-even
}

// ---------------- convert A (z_real|z_imag) -> bf16 [32768][1024] ----------------
__global__ void k_convA(const float* __restrict__ zr, const float* __restrict__ zi,
                        u16* __restrict__ A) {
    size_t t = (size_t)blockIdx.x * 256 + threadIdx.x;
    size_t base = t * 8;
    int tok = (int)(base >> 10);
    int k0  = (int)(base & 1023);
    const float* src = (k0 < 512) ? zr + (size_t)tok * 512 + k0
                                  : zi + (size_t)tok * 512 + (k0 - 512);
    float4 f0 = *(const float4*)src;
    float4 f1 = *(const float4*)(src + 4);
    u32 q0 = f2bf(f0.x) | ((u32)f2bf(f0.y) << 16);
    u32 q1 = f2bf(f0.z) | ((u32)f2bf(f0.w) << 16);
    u32 q2 = f2bf(f1.x) | ((u32)f2bf(f1.y) << 16);
    u32 q3 = f2bf(f1.z) | ((u32)f2bf(f1.w) << 16);
    *(uint4*)&A[base] = make_uint4(q0, q1, q2, q3);
}

// ---------------- convert B (codebook) -> bf16 + fused row norms ----------------
__global__ void k_convB(const float* __restrict__ cb, u16* __restrict__ B,
                        float* __restrict__ cnorm) {
    size_t t = (size_t)blockIdx.x * 256 + threadIdx.x;
    size_t base = t * 8;
    float4 f0 = *(const float4*)&cb[base];
    float4 f1 = *(const float4*)&cb[base + 4];
    u32 q0 = f2bf(f0.x) | ((u32)f2bf(f0.y) << 16);
    u32 q1 = f2bf(f0.z) | ((u32)f2bf(f0.w) << 16);
    u32 q2 = f2bf(f1.x) | ((u32)f2bf(f1.y) << 16);
    u32 q3 = f2bf(f1.z) | ((u32)f2bf(f1.w) << 16);
    *(uint4*)&B[base] = make_uint4(q0, q1, q2, q3);
    float nrm = f0.x * f0.x + f0.y * f0.y + f0.z * f0.z + f0.w * f0.w
              + f1.x * f1.x + f1.y * f1.y + f1.z * f1.z + f1.w * f1.w;
#pragma unroll
    for (int m = 32; m; m >>= 1) nrm += __shfl_xor(nrm, m, 64);
    __shared__ float part[4];
    int lane = threadIdx.x & 63, w = threadIdx.x >> 6;
    if (lane == 0) part[w] = nrm;
    __syncthreads();
    if (threadIdx.x == 0)   cnorm[blockIdx.x * 2]     = part[0] + part[1];
    if (threadIdx.x == 128) cnorm[blockIdx.x * 2 + 1] = part[2] + part[3];
}

// ---------------- bf16 MFMA screen (UNBIASED): top-2 vals + best idx per 128-col chunk ----------------
// 1D grid 1024, XCD-chunked swizzle.
// cand layout: candV[(chunk*2+s)*M + tok], candI[chunk*M + tok] (u16)
__global__ __launch_bounds__(256, 4) void k_screen(
    const u16* __restrict__ Ah, const u16* __restrict__ Bh,
    const float* __restrict__ cnorm,
    float* __restrict__ candV, u16* __restrict__ candI)
{
    __shared__ __align__(16) unsigned char smA[16384];   // [128 rows][64 k] bf16, XOR-swizzled
    __shared__ __align__(16) unsigned char smB[16384];   // [128 cols][64 k] bf16, XOR-swizzled
    __shared__ float mv[128][4];    // [row][wc*2+s]
    __shared__ float mi[128][2];    // [row][wc] best idx

    // XCD-aware swizzle: dispatch round-robins blockIdx%8 across XCDs.
    const int sblk = (blockIdx.x & 7) * 128 + (blockIdx.x >> 3);
    const int bx = sblk >> 2;          // 0..255 (token panel)
    const int by = sblk & 3;           // 0..3  (chunk quarter)

    const int tid  = threadIdx.x;
    const int lane = tid & 63;
    const int w    = tid >> 6;
    const int wr   = w >> 1, wc = w & 1;
    const int row0 = bx * 128;
    const int sBase = w * 256;

    for (int cc = 0; cc < 16; ++cc) {
        const int chunk = by * 16 + cc;
        const int colBase = chunk * 128;

        f32x4 acc[4][4];
#pragma unroll
        for (int m = 0; m < 4; ++m)
#pragma unroll
            for (int n = 0; n < 4; ++n) acc[m][n] = (f32x4){0.f, 0.f, 0.f, 0.f};

        for (int ks = 0; ks < 16; ++ks) {
            const int kk0 = ks * 64;
            __syncthreads();
#pragma unroll
            for (int i = 0; i < 4; ++i) {
                int slot = sBase + i * 64 + lane;
                int r = slot >> 3;
                int c = (slot & 7) ^ (r & 7);
                const u16* ga = Ah + ((size_t)(row0 + r) * KDIM + kk0 + c * 8);
                GLOAD_LDS16(ga, smA + (size_t)(sBase + i * 64) * 16);
                const u16* gb = Bh + ((size_t)(colBase + r) * KDIM + kk0 + c * 8);
                GLOAD_LDS16(gb, smB + (size_t)(sBase + i * 64) * 16);
            }
            __syncthreads();
#pragma unroll
            for (int h = 0; h < 2; ++h) {
                short8 af[4], bfr[4];
#pragma unroll
                for (int m = 0; m < 4; ++m) {
                    int r = wr * 64 + m * 16 + (lane & 15);
                    int byte = r * 128 + h * 64 + (lane >> 4) * 16;
                    byte ^= (r & 7) << 4;
                    af[m] = *(const short8*)(smA + byte);
                }
#pragma unroll
                for (int n = 0; n < 4; ++n) {
                    int r = wc * 64 + n * 16 + (lane & 15);
                    int byte = r * 128 + h * 64 + (lane >> 4) * 16;
                    byte ^= (r & 7) << 4;
                    bfr[n] = *(const short8*)(smB + byte);
                }
#pragma unroll
                for (int m = 0; m < 4; ++m)
#pragma unroll
                    for (int n = 0; n < 4; ++n)
                        acc[m][n] = __builtin_amdgcn_mfma_f32_16x16x32_bf16(
                            af[m], bfr[n], acc[m][n], 0, 0, 0);
            }
        }

        // epilogue: unbiased scores + per-chunk top-2 per row (value-only 2nd)
        float cn[4];
#pragma unroll
        for (int n = 0; n < 4; ++n)
            cn[n] = cnorm[colBase + wc * 64 + n * 16 + (lane & 15)];

#pragma unroll
        for (int m = 0; m < 4; ++m)
#pragma unroll
            for (int j = 0; j < 4; ++j) {
                int rowL = wr * 64 + m * 16 + (lane >> 4) * 4 + j;
                float v1 = INFINITY, v2 = INFINITY, i1v = 0.f;
#pragma unroll
                for (int n = 0; n < 4; ++n) {
                    float s = cn[n] - 2.0f * acc[m][n][j];
                    float ci = (float)(colBase + wc * 64 + n * 16 + (lane & 15));
                    if (s < v1) { v2 = v1; v1 = s; i1v = ci; }
                    else v2 = fminf(v2, s);
                }
#pragma unroll
                for (int msk = 1; msk < 16; msk <<= 1) {
                    float o1 = __shfl_xor(v1, msk, 16);
                    float oi = __shfl_xor(i1v, msk, 16);
                    float o2 = __shfl_xor(v2, msk, 16);
                    float n2 = fminf(fminf(v2, o2), fmaxf(v1, o1));
                    if (o1 < v1) { v1 = o1; i1v = oi; }
                    v2 = n2;
                }
                if ((lane & 15) == 0) {
                    mv[rowL][wc * 2] = v1;  mv[rowL][wc * 2 + 1] = v2;
                    mi[rowL][wc] = i1v;
                }
            }
        __syncthreads();
        if (tid < 128) {
            float a1 = mv[tid][0], a2 = mv[tid][1], ai = mi[tid][0];
            float b1 = mv[tid][2], b2 = mv[tid][3], bi = mi[tid][1];
            float best  = fminf(a1, b1);
            float bidx  = (b1 < a1) ? bi : ai;
            float secnd = fminf(fminf(a2, b2), fmaxf(a1, b1));
            size_t tcol = (size_t)(row0 + tid);
            candV[(size_t)(chunk * 2 + 0) * M_TOK + tcol] = best;
            candV[(size_t)(chunk * 2 + 1) * M_TOK + tcol] = secnd;
            candI[(size_t)chunk * M_TOK + tcol]           = (u16)bidx;
        }
        // mv/mi reuse protected by barriers inside next chunk's K-loop
    }
}

// ---------------- zero scratch counters (after screen; A_bf16 area is dead) ----------------
__global__ void k_zero(u32* __restrict__ counts, u32* __restrict__ cursors,
                       float* __restrict__ out_loss) {
    int i = blockIdx.x * 256 + threadIdx.x;
    if (i < NSYM) { counts[i] = 0; cursors[i] = 0; }
    if (i == 0) out_loss[0] = 0.0f;
}

// ---------------- select: exact fp64 rescore (with bias) of windowed candidates ----------------
#define SEL_TOK 64
__device__ __forceinline__ void rescore(
    const float* __restrict__ codebook, const float* __restrict__ adjacency,
    const double* zreg, int prw, int col, int lane, double& bestS, int& bestI)
{
    const float* crow = codebook + (size_t)col * KDIM;
    double dot = 0.0, cn2 = 0.0;
#pragma unroll
    for (int j = 0; j < 16; ++j) {
        double c = (double)crow[lane + 64 * j];
        dot += c * zreg[j]; cn2 += c * c;
    }
#pragma unroll
    for (int m = 32; m; m >>= 1) {
        dot += __shfl_xor(dot, m, 64);
        cn2 += __shfl_xor(cn2, m, 64);
    }
    double a = (double)adjacency[(size_t)prw * NSYM + col];
    double sc = cn2 - 2.0 * dot - (double)GBS_F / (1.0 + exp(-a));
    if (sc < bestS || (sc == bestS && col < bestI)) { bestS = sc; bestI = col; }
}

__global__ __launch_bounds__(256) void k_select(
    const float* __restrict__ zr, const float* __restrict__ zi,
    const int* __restrict__ prev,
    const float* __restrict__ codebook,
    const float* __restrict__ adjacency,
    const float* __restrict__ candV, const u16* __restrict__ candI,
    float* __restrict__ out_idx, u32* __restrict__ counts)
{
    __shared__ float sv[128][SEL_TOK + 1];
    __shared__ u16   si[64][SEL_TOK + 2];
    const int tok0 = blockIdx.x * SEL_TOK;
    const int w = threadIdx.x >> 6, lane = threadIdx.x & 63;

    for (int e = w; e < 128; e += 4)
        sv[e][lane] = candV[(size_t)e * M_TOK + tok0 + lane];
    for (int e = w; e < 64; e += 4)
        si[e][lane] = candI[(size_t)e * M_TOK + tok0 + lane];
    __syncthreads();

    for (int tt = 0; tt < 16; ++tt) {
        const int t = w * 16 + tt;
        const int tok = tok0 + t;
        float v1 = sv[lane * 2 + 0][t];
        float v2 = sv[lane * 2 + 1][t];
        int   i1 = (int)si[lane][t];

        float mm = v1;
#pragma unroll
        for (int m = 32; m; m >>= 1) mm = fminf(mm, __shfl_xor(mm, m, 64));
        const float thr = mm + WIN_F;

        unsigned long long m1 = __ballot(v1 <= thr);
        unsigned long long m2 = __ballot(v2 <= thr);

        int bestI;
        if (__popcll(m1) == 1 && m2 == 0) {
            int c = __ffsll(m1) - 1;
            bestI = __shfl(i1, c, 64);
        } else {
            double zreg[16];
#pragma unroll
            for (int j = 0; j < 8; ++j)
                zreg[j] = (double)zr[(size_t)tok * LAT + lane + 64 * j];
#pragma unroll
            for (int j = 0; j < 8; ++j)
                zreg[8 + j] = (double)zi[(size_t)tok * LAT + lane + 64 * j];
            const int prw = prev[tok];

            double bestS = DBL_MAX; bestI = 0x7FFFFFFF;
            unsigned long long singles = m1 & ~m2, chunks = m2;
            while (singles) { int c = __ffsll(singles) - 1; singles &= singles - 1;
                rescore(codebook, adjacency, zreg, prw, __shfl(i1, c, 64), lane, bestS, bestI); }
            while (chunks) { int c = __ffsll(chunks) - 1; chunks &= chunks - 1;
                for (int q = 0; q < 128; ++q)
                    rescore(codebook, adjacency, zreg, prw, c * 128 + q, lane, bestS, bestI); }
        }
        if (lane == 0) {
            out_idx[tok] = (float)bestI;
            atomicAdd(&counts[bestI], 1u);
        }
    }
}

// ---------------- scan: offsets, new_cluster_size, n_total ----------------
__global__ __launch_bounds__(1024) void k_scan(
    const u32* __restrict__ counts, const float* __restrict__ cs_old,
    float* __restrict__ out_cs, u32* __restrict__ offsets,
    float* __restrict__ scal)     // scal[0]=ntot, scal[1]=denom
{
    const int tid = threadIdx.x;
    const int lane = tid & 63, w = tid >> 6;
    const int base = tid * 8;
    u32 c[8], pre[8], T = 0;
#pragma unroll
    for (int q = 0; q < 8; ++q) { c[q] = counts[base + q]; pre[q] = T; T += c[q]; }
    u32 inc = T;
#pragma unroll
    for (int d = 1; d < 64; d <<= 1) {
        u32 v = __shfl_up(inc, d, 64);
        if (lane >= d) inc += v;
    }
    __shared__ u32 wt[16];
    if (lane == 63) wt[w] = inc;
    __syncthreads();
    if (tid < 16) {
        u32 v = wt[tid];
#pragma unroll
        for (int d = 1; d < 16; d <<= 1) {
            u32 o = __shfl_up(v, d, 16);
            if (tid >= d) v += o;
        }
        wt[tid] = v;
    }
    __syncthreads();
    u32 ex = (w ? wt[w - 1] : 0) + inc - T;
#pragma unroll
    for (int q = 0; q < 8; ++q) offsets[base + q] = ex + pre[q];

    float nt = 0.0f;
#pragma unroll
    for (int q = 0; q < 8; ++q) {
        float ncs = cs_old[base + q] * DECAY_F + OMD_F * (float)c[q];
        out_cs[base + q] = ncs;
        nt += ncs;
    }
#pragma unroll
    for (int m = 32; m; m >>= 1) nt += __shfl_xor(nt, m, 64);
    __shared__ float red[16];
    if (lane == 0) red[w] = nt;
    __syncthreads();
    if (tid == 0) {
        float s = 0.0f;
#pragma unroll
        for (int i = 0; i < 16; ++i) s += red[i];
        scal[0] = s;
        scal[1] = s + (float)NSYM * EPS_F;
    }
}

// ---------------- place: token lists per symbol ----------------
__global__ void k_place(const float* __restrict__ idxf, const u32* __restrict__ offsets,
                        u32* __restrict__ cursors, u32* __restrict__ list) {
    int t = blockIdx.x * 256 + threadIdx.x;
    int s = (int)idxf[t];
    u32 slot = atomicAdd(&cursors[s], 1u);
    list[offsets[s] + slot] = (u32)t;
}

// ---------------- emit: new_embed_avg + new_codebook per symbol (no atomics) ----------------
__global__ __launch_bounds__(256) void k_emit(
    const float* __restrict__ zr, const float* __restrict__ zi,
    const float* __restrict__ embed_avg,
    const u32* __restrict__ counts, const u32* __restrict__ offsets,
    const u32* __restrict__ list, const float* __restrict__ out_cs,
    const float* __restrict__ scal,
    float* __restrict__ out_ea, float* __restrict__ out_cb)
{
    const int s = blockIdx.x;
    const u32 cnt = counts[s], off = offsets[s];
    const int j = threadIdx.x * 4;
    float a0 = 0.f, a1 = 0.f, a2 = 0.f, a3 = 0.f;
    for (u32 n = 0; n < cnt; ++n) {
        int t = (int)list[off + n];
        const float* src = (j < 512) ? zr + (size_t)t * 512 + j
                                     : zi + (size_t)t * 512 + (j - 512);
        float4 v = *(const float4*)src;
        a0 += v.x; a1 += v.y; a2 += v.z; a3 += v.w;
    }
    float4 ea = *(const float4*)&embed_avg[(size_t)s * KDIM + j];
    float4 nea = make_float4(ea.x * DECAY_F + a0 * OMD_F,
                             ea.y * DECAY_F + a1 * OMD_F,
                             ea.z * DECAY_F + a2 * OMD_F,
                             ea.w * DECAY_F + a3 * OMD_F);
    *(float4*)&out_ea[(size_t)s * KDIM + j] = nea;
    float ntot = scal[0], denom = scal[1];
    float cs = (out_cs[s] + EPS_F) / denom * ntot;
    float inv = 1.0f / cs;
    *(float4*)&out_cb[(size_t)s * KDIM + j] =
        make_float4(nea.x * inv, nea.y * inv, nea.z * inv, nea.w * inv);
}

// ---------------- zq: gather codebook rows, write output0, loss ----------------
__global__ __launch_bounds__(256) void k_zq(
    const float* __restrict__ zr, const float* __restrict__ zi,
    const float* __restrict__ codebook, const float* __restrict__ idxf,
    float* __restrict__ out_zc, float* __restrict__ out_loss, int interleaved)
{
    const int w = threadIdx.x >> 6, lane = threadIdx.x & 63;
    const int tok = blockIdx.x * 4 + w;
    const int mi = (int)idxf[tok];
    const int j0 = lane * 8;
    float4 re0 = *(const float4*)&codebook[(size_t)mi * KDIM + j0];
    float4 re1 = *(const float4*)&codebook[(size_t)mi * KDIM + j0 + 4];
    float4 im0 = *(const float4*)&codebook[(size_t)mi * KDIM + LAT + j0];
    float4 im1 = *(const float4*)&codebook[(size_t)mi * KDIM + LAT + j0 + 4];
    float4 zr0 = *(const float4*)&zr[(size_t)tok * LAT + j0];
    float4 zr1 = *(const float4*)&zr[(size_t)tok * LAT + j0 + 4];
    float4 zi0 = *(const float4*)&zi[(size_t)tok * LAT + j0];
    float4 zi1 = *(const float4*)&zi[(size_t)tok * LAT + j0 + 4];
    if (interleaved) {
        float2* dst = (float2*)out_zc + (size_t)tok * LAT + j0;
        dst[0] = make_float2(re0.x, im0.x); dst[1] = make_float2(re0.y, im0.y);
        dst[2] = make_float2(re0.z, im0.z); dst[3] = make_float2(re0.w, im0.w);
        dst[4] = make_float2(re1.x, im1.x); dst[5] = make_float2(re1.y, im1.y);
        dst[6] = make_float2(re1.z, im1.z); dst[7] = make_float2(re1.w, im1.w);
    } else {
        *(float4*)&out_zc[(size_t)tok * LAT + j0]     = re0;
        *(float4*)&out_zc[(size_t)tok * LAT + j0 + 4] = re1;
    }
    float l = 0.f;
    l += (re0.x-zr0.x)*(re0.x-zr0.x) + (re0.y-zr0.y)*(re0.y-zr0.y)
       + (re0.z-zr0.z)*(re0.z-zr0.z) + (re0.w-zr0.w)*(re0.w-zr0.w);
    l += (re1.x-zr1.x)*(re1.x-zr1.x) + (re1.y-zr1.y)*(re1.y-zr1.y)
       + (re1.z-zr1.z)*(re1.z-zr1.z) + (re1.w-zr1.w)*(re1.w-zr1.w);
    l += (im0.x-zi0.x)*(im0.x-zi0.x) + (im0.y-zi0.y)*(im0.y-zi0.y)
       + (im0.z-zi0.z)*(im0.z-zi0.z) + (im0.w-zi0.w)*(im0.w-zi0.w);
    l += (im1.x-zi1.x)*(im1.x-zi1.x) + (im1.y-zi1.y)*(im1.y-zi1.y)
       + (im1.z-zi1.z)*(im1.z-zi1.z) + (im1.w-zi1.w)*(im1.w-zi1.w);
#pragma unroll
    for (int m = 32; m; m >>= 1) l += __shfl_xor(l, m, 64);
    if (lane == 0) atomicAdd(out_loss, l);
}

// ---------------- finalize loss ----------------
__global__ void k_fin(float* __restrict__ out_loss) {
    out_loss[0] = out_loss[0] * 1.25f / 33554432.0f;   // *(1+0.25)/(M*KDIM)
}

extern "C" void kernel_launch(void* const* d_in, const int* in_sizes, int n_in,
                              void* d_out, int out_size, void* d_ws, size_t ws_size,
                              hipStream_t stream) {
    const float* z_real     = (const float*)d_in[0];
    const float* z_imag     = (const float*)d_in[1];
    const int*   prev_idx   = (const int*)d_in[2];
    const float* codebook   = (const float*)d_in[3];
    const float* cluster_sz = (const float*)d_in[4];
    const float* embed_avg  = (const float*)d_in[5];
    const float* adjacency  = (const float*)d_in[6];

    float* out = (float*)d_out;

    const size_t REST = 1 + (size_t)M_TOK + (size_t)NSYM * KDIM + NSYM
                      + (size_t)NSYM * KDIM;               // 16,818,177
    size_t zc_n = (size_t)out_size - REST;
    const size_t n_z = (size_t)M_TOK * LAT;
    int interleaved = (zc_n >= 2 * n_z) ? 1 : 0;

    float* out_zc   = out;
    float* out_loss = out + zc_n;
    float* out_idx  = out + zc_n + 1;
    float* out_cb   = out + zc_n + 1 + M_TOK;
    float* out_cs   = out_cb + (size_t)NSYM * KDIM;
    float* out_ea   = out_cs + NSYM;

    // scratch, phase 1 (screen inputs), carved from output regions:
    u16*   A_hi  = (u16*)out_zc;                       // 67.1 MB (zc region)
    u16*   B_hi  = (u16*)out_cb;                       // 16.8 MB (cb region)
    float* cnorm = out_cb + 4194304;                   // 32 KB after B_hi
    float* candV = out_ea;                             // 16.8 MB [128][M]
    u16*   candI = (u16*)(out_cb + 4202496);           // 4.2 MB  [64][M] (cb free area)

    // scratch, phase 2 (EMA sort), in zc region (A_hi dead after screen; k_zq runs last):
    u32*   counts  = (u32*)out_zc;                     // 32 KB
    u32*   cursors = counts + NSYM;                    // 32 KB
    u32*   offsets = cursors + NSYM;                   // 32 KB
    u32*   list    = offsets + NSYM;                   // 128 KB
    float* scal    = (float*)(list + M_TOK);           // 8 B

    k_convA<<<16384, 256, 0, stream>>>(z_real, z_imag, A_hi);
    k_convB<<<4096, 256, 0, stream>>>(codebook, B_hi, cnorm);
    k_screen<<<1024, 256, 0, stream>>>(A_hi, B_hi, cnorm, candV, candI);
    k_zero<<<32, 256, 0, stream>>>(counts, cursors, out_loss);
    k_select<<<M_TOK / SEL_TOK, 256, 0, stream>>>(z_real, z_imag, prev_idx,
                                                  codebook, adjacency,
                                                  candV, candI, out_idx, counts);
    k_scan<<<1, 1024, 0, stream>>>(counts, cluster_sz, out_cs, offsets, scal);
    k_place<<<M_TOK / 256, 256, 0, stream>>>(out_idx, offsets, cursors, list);
    k_emit<<<NSYM, 256, 0, stream>>>(z_real, z_imag, embed_avg, counts, offsets,
                                     list, out_cs, scal, out_ea, out_cb);
    k_zq<<<M_TOK / 4, 256, 0, stream>>>(z_real, z_imag, codebook, out_idx,
                                        out_zc, out_loss, interleaved);
    k_fin<<<1, 1, 0, stream>>>(out_loss);
}

// Round 7
// 1501.935 us; speedup vs baseline: 1.0470x; 1.0470x over previous
//
#include <hip/hip_runtime.h>
#include <math.h>
#include <float.h>

#define M_TOK   32768
#define NSYM    8192
#define KDIM    1024
#define LAT     512

#define DECAY_F 0.995f
#define OMD_F   0.005f
#define GBS_F   0.7f
#define EPS_F   1e-6f
#define WIN_F   3.0f            // 0.7 bias + 2*(6-sigma bf16 screen err) + margin

typedef unsigned short u16;
typedef unsigned int   u32;
typedef short short8 __attribute__((ext_vector_type(8)));
typedef float f32x4  __attribute__((ext_vector_type(4)));

#define GLOAD_LDS16(g, l) \
    __builtin_amdgcn_global_load_lds((const __attribute__((address_space(1))) u32*)(g), \
                                     (__attribute__((address_space(3))) u32*)(l), 16, 0, 0)

__device__ __forceinline__ u16 f2bf(float f) {
    u32 u = __float_as_uint(f);
    return (u16)((u + 0x7FFF + ((u >> 16) & 1)) >> 16);   // round-to-nearest-even
}

// ---------------- convert A (z_real|z_imag) -> bf16 [32768][1024] ----------------
__global__ void k_convA(const float* __restrict__ zr, const float* __restrict__ zi,
                        u16* __restrict__ A) {
    size_t t = (size_t)blockIdx.x * 256 + threadIdx.x;
    size_t base = t * 8;
    int tok = (int)(base >> 10);
    int k0  = (int)(base & 1023);
    const float* src = (k0 < 512) ? zr + (size_t)tok * 512 + k0
                                  : zi + (size_t)tok * 512 + (k0 - 512);
    float4 f0 = *(const float4*)src;
    float4 f1 = *(const float4*)(src + 4);
    u32 q0 = f2bf(f0.x) | ((u32)f2bf(f0.y) << 16);
    u32 q1 = f2bf(f0.z) | ((u32)f2bf(f0.w) << 16);
    u32 q2 = f2bf(f1.x) | ((u32)f2bf(f1.y) << 16);
    u32 q3 = f2bf(f1.z) | ((u32)f2bf(f1.w) << 16);
    *(uint4*)&A[base] = make_uint4(q0, q1, q2, q3);
}

// ---------------- convert B (codebook) -> bf16 + fused row norms ----------------
__global__ void k_convB(const float* __restrict__ cb, u16* __restrict__ B,
                        float* __restrict__ cnorm) {
    size_t t = (size_t)blockIdx.x * 256 + threadIdx.x;
    size_t base = t * 8;
    float4 f0 = *(const float4*)&cb[base];
    float4 f1 = *(const float4*)&cb[base + 4];
    u32 q0 = f2bf(f0.x) | ((u32)f2bf(f0.y) << 16);
    u32 q1 = f2bf(f0.z) | ((u32)f2bf(f0.w) << 16);
    u32 q2 = f2bf(f1.x) | ((u32)f2bf(f1.y) << 16);
    u32 q3 = f2bf(f1.z) | ((u32)f2bf(f1.w) << 16);
    *(uint4*)&B[base] = make_uint4(q0, q1, q2, q3);
    float nrm = f0.x * f0.x + f0.y * f0.y + f0.z * f0.z + f0.w * f0.w
              + f1.x * f1.x + f1.y * f1.y + f1.z * f1.z + f1.w * f1.w;
#pragma unroll
    for (int m = 32; m; m >>= 1) nrm += __shfl_xor(nrm, m, 64);
    __shared__ float part[4];
    int lane = threadIdx.x & 63, w = threadIdx.x >> 6;
    if (lane == 0) part[w] = nrm;
    __syncthreads();
    if (threadIdx.x == 0)   cnorm[blockIdx.x * 2]     = part[0] + part[1];
    if (threadIdx.x == 128) cnorm[blockIdx.x * 2 + 1] = part[2] + part[3];
}

// ---------------- bf16 MFMA screen (UNBIASED): top-2 vals + best idx per 64-col HALF ----------------
// 1D grid 1024, XCD-chunked swizzle.
// cand layout: halfIdx = chunk*2 + wc  (0..127), covering cols [halfIdx*64, +64)
//   candV[(halfIdx*2+s)*M + tok]  (s=0 best, s=1 second val of the half)
//   candI[halfIdx*M + tok]        (u16 best idx of the half)
__global__ __launch_bounds__(256, 4) void k_screen(
    const u16* __restrict__ Ah, const u16* __restrict__ Bh,
    const float* __restrict__ cnorm,
    float* __restrict__ candV, u16* __restrict__ candI)
{
    __shared__ __align__(16) unsigned char smA[16384];   // [128 rows][64 k] bf16, XOR-swizzled
    __shared__ __align__(16) unsigned char smB[16384];   // [128 cols][64 k] bf16, XOR-swizzled
    __shared__ float smv[128][2][2];    // [row][wc][s]
    __shared__ float smi[128][2];       // [row][wc] best idx

    // XCD-aware swizzle: dispatch round-robins blockIdx%8 across XCDs.
    const int sblk = (blockIdx.x & 7) * 128 + (blockIdx.x >> 3);
    const int bx = sblk >> 2;          // 0..255 (token panel)
    const int by = sblk & 3;           // 0..3  (chunk quarter)

    const int tid  = threadIdx.x;
    const int lane = tid & 63;
    const int w    = tid >> 6;
    const int wr   = w >> 1, wc = w & 1;
    const int row0 = bx * 128;
    const int sBase = w * 256;

    for (int cc = 0; cc < 16; ++cc) {
        const int chunk = by * 16 + cc;
        const int colBase = chunk * 128;

        f32x4 acc[4][4];
#pragma unroll
        for (int m = 0; m < 4; ++m)
#pragma unroll
            for (int n = 0; n < 4; ++n) acc[m][n] = (f32x4){0.f, 0.f, 0.f, 0.f};

        for (int ks = 0; ks < 16; ++ks) {
            const int kk0 = ks * 64;
            __syncthreads();
#pragma unroll
            for (int i = 0; i < 4; ++i) {
                int slot = sBase + i * 64 + lane;
                int r = slot >> 3;
                int c = (slot & 7) ^ (r & 7);
                const u16* ga = Ah + ((size_t)(row0 + r) * KDIM + kk0 + c * 8);
                GLOAD_LDS16(ga, smA + (size_t)(sBase + i * 64) * 16);
                const u16* gb = Bh + ((size_t)(colBase + r) * KDIM + kk0 + c * 8);
                GLOAD_LDS16(gb, smB + (size_t)(sBase + i * 64) * 16);
            }
            __syncthreads();
#pragma unroll
            for (int h = 0; h < 2; ++h) {
                short8 af[4], bfr[4];
#pragma unroll
                for (int m = 0; m < 4; ++m) {
                    int r = wr * 64 + m * 16 + (lane & 15);
                    int byte = r * 128 + h * 64 + (lane >> 4) * 16;
                    byte ^= (r & 7) << 4;
                    af[m] = *(const short8*)(smA + byte);
                }
#pragma unroll
                for (int n = 0; n < 4; ++n) {
                    int r = wc * 64 + n * 16 + (lane & 15);
                    int byte = r * 128 + h * 64 + (lane >> 4) * 16;
                    byte ^= (r & 7) << 4;
                    bfr[n] = *(const short8*)(smB + byte);
                }
#pragma unroll
                for (int m = 0; m < 4; ++m)
#pragma unroll
                    for (int n = 0; n < 4; ++n)
                        acc[m][n] = __builtin_amdgcn_mfma_f32_16x16x32_bf16(
                            af[m], bfr[n], acc[m][n], 0, 0, 0);
            }
        }

        // epilogue: unbiased scores + per-HALF top-2 per row (value-only 2nd)
        float cn[4];
#pragma unroll
        for (int n = 0; n < 4; ++n)
            cn[n] = cnorm[colBase + wc * 64 + n * 16 + (lane & 15)];

#pragma unroll
        for (int m = 0; m < 4; ++m)
#pragma unroll
            for (int j = 0; j < 4; ++j) {
                int rowL = wr * 64 + m * 16 + (lane >> 4) * 4 + j;
                float v1 = INFINITY, v2 = INFINITY, i1v = 0.f;
#pragma unroll
                for (int n = 0; n < 4; ++n) {
                    float s = cn[n] - 2.0f * acc[m][n][j];
                    float ci = (float)(colBase + wc * 64 + n * 16 + (lane & 15));
                    if (s < v1) { v2 = v1; v1 = s; i1v = ci; }
                    else v2 = fminf(v2, s);
                }
#pragma unroll
                for (int msk = 1; msk < 16; msk <<= 1) {
                    float o1 = __shfl_xor(v1, msk, 16);
                    float oi = __shfl_xor(i1v, msk, 16);
                    float o2 = __shfl_xor(v2, msk, 16);
                    float n2 = fminf(fminf(v2, o2), fmaxf(v1, o1));
                    if (o1 < v1) { v1 = o1; i1v = oi; }
                    v2 = n2;
                }
                if ((lane & 15) == 0) {
                    smv[rowL][wc][0] = v1;  smv[rowL][wc][1] = v2;
                    smi[rowL][wc] = i1v;
                }
            }
        __syncthreads();
        {
            int half = tid >> 7;          // 0..1
            int row  = tid & 127;
            float v1 = smv[row][half][0], v2 = smv[row][half][1];
            float iv = smi[row][half];
            size_t tcol = (size_t)(row0 + row);
            int halfIdx = chunk * 2 + half;
            candV[(size_t)(halfIdx * 2 + 0) * M_TOK + tcol] = v1;
            candV[(size_t)(halfIdx * 2 + 1) * M_TOK + tcol] = v2;
            candI[(size_t)halfIdx * M_TOK + tcol]           = (u16)iv;
        }
        // smv/smi reuse protected by barriers inside next chunk's K-loop
    }
}

// ---------------- zero scratch counters (after screen; A_bf16 area is dead) ----------------
__global__ void k_zero(u32* __restrict__ counts, u32* __restrict__ cursors,
                       float* __restrict__ out_loss) {
    int i = blockIdx.x * 256 + threadIdx.x;
    if (i < NSYM) { counts[i] = 0; cursors[i] = 0; }
    if (i == 0) out_loss[0] = 0.0f;
}

// ---------------- select: exact fp64 rescore (with bias) of windowed candidates ----------------
#define SEL_TOK 32
__device__ __forceinline__ void rescore(
    const float* __restrict__ codebook, const float* __restrict__ adjacency,
    const double* zreg, int prw, int col, int lane, double& bestS, int& bestI)
{
    const float* crow = codebook + (size_t)col * KDIM;
    double dot = 0.0, cn2 = 0.0;
#pragma unroll
    for (int j = 0; j < 16; ++j) {
        double c = (double)crow[lane + 64 * j];
        dot += c * zreg[j]; cn2 += c * c;
    }
#pragma unroll
    for (int m = 32; m; m >>= 1) {
        dot += __shfl_xor(dot, m, 64);
        cn2 += __shfl_xor(cn2, m, 64);
    }
    double a = (double)adjacency[(size_t)prw * NSYM + col];
    double sc = cn2 - 2.0 * dot - (double)GBS_F / (1.0 + exp(-a));
    if (sc < bestS || (sc == bestS && col < bestI)) { bestS = sc; bestI = col; }
}

__global__ __launch_bounds__(256) void k_select(
    const float* __restrict__ zr, const float* __restrict__ zi,
    const int* __restrict__ prev,
    const float* __restrict__ codebook,
    const float* __restrict__ adjacency,
    const float* __restrict__ candV, const u16* __restrict__ candI,
    float* __restrict__ out_idx, u32* __restrict__ counts)
{
    __shared__ float sv[256][SEL_TOK + 1];
    __shared__ u16   si[128][SEL_TOK + 2];
    const int tok0 = blockIdx.x * SEL_TOK;
    const int w = threadIdx.x >> 6, lane = threadIdx.x & 63;

    for (int idx = threadIdx.x; idx < 256 * SEL_TOK; idx += 256) {
        int e = idx >> 5, t = idx & (SEL_TOK - 1);
        sv[e][t] = candV[(size_t)e * M_TOK + tok0 + t];
    }
    for (int idx = threadIdx.x; idx < 128 * SEL_TOK; idx += 256) {
        int e = idx >> 5, t = idx & (SEL_TOK - 1);
        si[e][t] = candI[(size_t)e * M_TOK + tok0 + t];
    }
    __syncthreads();

    for (int tt = 0; tt < SEL_TOK / 4; ++tt) {
        const int t = w * (SEL_TOK / 4) + tt;
        const int tok = tok0 + t;
        // lane owns half-chunks h0 = 2*lane, h1 = 2*lane+1 (cols lane*128.. +64 / +64..+128)
        float va1 = sv[4 * lane + 0][t];
        float va2 = sv[4 * lane + 1][t];
        float vb1 = sv[4 * lane + 2][t];
        float vb2 = sv[4 * lane + 3][t];
        int   ia  = (int)si[2 * lane + 0][t];
        int   ib  = (int)si[2 * lane + 1][t];

        float mm = fminf(va1, vb1);
#pragma unroll
        for (int m = 32; m; m >>= 1) mm = fminf(mm, __shfl_xor(mm, m, 64));
        const float thr = mm + WIN_F;

        unsigned long long m1a = __ballot(va1 <= thr);
        unsigned long long m1b = __ballot(vb1 <= thr);
        unsigned long long mha = __ballot(va2 <= thr);
        unsigned long long mhb = __ballot(vb2 <= thr);

        int bestI;
        if ((mha | mhb) == 0 && __popcll(m1a) + __popcll(m1b) == 1) {
            if (m1a) bestI = __shfl(ia, __ffsll(m1a) - 1, 64);
            else     bestI = __shfl(ib, __ffsll(m1b) - 1, 64);
        } else {
            double zreg[16];
#pragma unroll
            for (int j = 0; j < 8; ++j)
                zreg[j] = (double)zr[(size_t)tok * LAT + lane + 64 * j];
#pragma unroll
            for (int j = 0; j < 8; ++j)
                zreg[8 + j] = (double)zi[(size_t)tok * LAT + lane + 64 * j];
            const int prw = prev[tok];

            double bestS = DBL_MAX; bestI = 0x7FFFFFFF;
            unsigned long long sa = m1a & ~mha, sb = m1b & ~mhb;
            while (sa) { int c = __ffsll(sa) - 1; sa &= sa - 1;
                rescore(codebook, adjacency, zreg, prw, __shfl(ia, c, 64), lane, bestS, bestI); }
            while (sb) { int c = __ffsll(sb) - 1; sb &= sb - 1;
                rescore(codebook, adjacency, zreg, prw, __shfl(ib, c, 64), lane, bestS, bestI); }
            while (mha) { int c = __ffsll(mha) - 1; mha &= mha - 1;
                for (int q = 0; q < 64; ++q)
                    rescore(codebook, adjacency, zreg, prw, c * 128 + q, lane, bestS, bestI); }
            while (mhb) { int c = __ffsll(mhb) - 1; mhb &= mhb - 1;
                for (int q = 0; q < 64; ++q)
                    rescore(codebook, adjacency, zreg, prw, c * 128 + 64 + q, lane, bestS, bestI); }
        }
        if (lane == 0) {
            out_idx[tok] = (float)bestI;
            atomicAdd(&counts[bestI], 1u);
        }
    }
}

// ---------------- scan: offsets, new_cluster_size, n_total ----------------
__global__ __launch_bounds__(1024) void k_scan(
    const u32* __restrict__ counts, const float* __restrict__ cs_old,
    float* __restrict__ out_cs, u32* __restrict__ offsets,
    float* __restrict__ scal)     // scal[0]=ntot, scal[1]=denom
{
    const int tid = threadIdx.x;
    const int lane = tid & 63, w = tid >> 6;
    const int base = tid * 8;
    u32 c[8], pre[8], T = 0;
#pragma unroll
    for (int q = 0; q < 8; ++q) { c[q] = counts[base + q]; pre[q] = T; T += c[q]; }
    u32 inc = T;
#pragma unroll
    for (int d = 1; d < 64; d <<= 1) {
        u32 v = __shfl_up(inc, d, 64);
        if (lane >= d) inc += v;
    }
    __shared__ u32 wt[16];
    if (lane == 63) wt[w] = inc;
    __syncthreads();
    if (tid < 16) {
        u32 v = wt[tid];
#pragma unroll
        for (int d = 1; d < 16; d <<= 1) {
            u32 o = __shfl_up(v, d, 16);
            if (tid >= d) v += o;
        }
        wt[tid] = v;
    }
    __syncthreads();
    u32 ex = (w ? wt[w - 1] : 0) + inc - T;
#pragma unroll
    for (int q = 0; q < 8; ++q) offsets[base + q] = ex + pre[q];

    float nt = 0.0f;
#pragma unroll
    for (int q = 0; q < 8; ++q) {
        float ncs = cs_old[base + q] * DECAY_F + OMD_F * (float)c[q];
        out_cs[base + q] = ncs;
        nt += ncs;
    }
#pragma unroll
    for (int m = 32; m; m >>= 1) nt += __shfl_xor(nt, m, 64);
    __shared__ float red[16];
    if (lane == 0) red[w] = nt;
    __syncthreads();
    if (tid == 0) {
        float s = 0.0f;
#pragma unroll
        for (int i = 0; i < 16; ++i) s += red[i];
        scal[0] = s;
        scal[1] = s + (float)NSYM * EPS_F;
    }
}

// ---------------- place: token lists per symbol ----------------
__global__ void k_place(const float* __restrict__ idxf, const u32* __restrict__ offsets,
                        u32* __restrict__ cursors, u32* __restrict__ list) {
    int t = blockIdx.x * 256 + threadIdx.x;
    int s = (int)idxf[t];
    u32 slot = atomicAdd(&cursors[s], 1u);
    list[offsets[s] + slot] = (u32)t;
}

// ---------------- emit: new_embed_avg + new_codebook per symbol (no atomics) ----------------
__global__ __launch_bounds__(256) void k_emit(
    const float* __restrict__ zr, const float* __restrict__ zi,
    const float* __restrict__ embed_avg,
    const u32* __restrict__ counts, const u32* __restrict__ offsets,
    const u32* __restrict__ list, const float* __restrict__ out_cs,
    const float* __restrict__ scal,
    float* __restrict__ out_ea, float* __restrict__ out_cb)
{
    const int s = blockIdx.x;
    const u32 cnt = counts[s], off = offsets[s];
    const int j = threadIdx.x * 4;
    float a0 = 0.f, a1 = 0.f, a2 = 0.f, a3 = 0.f;
    for (u32 n = 0; n < cnt; ++n) {
        int t = (int)list[off + n];
        const float* src = (j < 512) ? zr + (size_t)t * 512 + j
                                     : zi + (size_t)t * 512 + (j - 512);
        float4 v = *(const float4*)src;
        a0 += v.x; a1 += v.y; a2 += v.z; a3 += v.w;
    }
    float4 ea = *(const float4*)&embed_avg[(size_t)s * KDIM + j];
    float4 nea = make_float4(ea.x * DECAY_F + a0 * OMD_F,
                             ea.y * DECAY_F + a1 * OMD_F,
                             ea.z * DECAY_F + a2 * OMD_F,
                             ea.w * DECAY_F + a3 * OMD_F);
    *(float4*)&out_ea[(size_t)s * KDIM + j] = nea;
    float ntot = scal[0], denom = scal[1];
    float cs = (out_cs[s] + EPS_F) / denom * ntot;
    float inv = 1.0f / cs;
    *(float4*)&out_cb[(size_t)s * KDIM + j] =
        make_float4(nea.x * inv, nea.y * inv, nea.z * inv, nea.w * inv);
}

// ---------------- zq: gather codebook rows, write output0, loss ----------------
__global__ __launch_bounds__(256) void k_zq(
    const float* __restrict__ zr, const float* __restrict__ zi,
    const float* __restrict__ codebook, const float* __restrict__ idxf,
    float* __restrict__ out_zc, float* __restrict__ out_loss, int interleaved)
{
    const int w = threadIdx.x >> 6, lane = threadIdx.x & 63;
    const int tok = blockIdx.x * 4 + w;
    const int mi = (int)idxf[tok];
    const int j0 = lane * 8;
    float4 re0 = *(const float4*)&codebook[(size_t)mi * KDIM + j0];
    float4 re1 = *(const float4*)&codebook[(size_t)mi * KDIM + j0 + 4];
    float4 im0 = *(const float4*)&codebook[(size_t)mi * KDIM + LAT + j0];
    float4 im1 = *(const float4*)&codebook[(size_t)mi * KDIM + LAT + j0 + 4];
    float4 zr0 = *(const float4*)&zr[(size_t)tok * LAT + j0];
    float4 zr1 = *(const float4*)&zr[(size_t)tok * LAT + j0 + 4];
    float4 zi0 = *(const float4*)&zi[(size_t)tok * LAT + j0];
    float4 zi1 = *(const float4*)&zi[(size_t)tok * LAT + j0 + 4];
    if (interleaved) {
        float2* dst = (float2*)out_zc + (size_t)tok * LAT + j0;
        dst[0] = make_float2(re0.x, im0.x); dst[1] = make_float2(re0.y, im0.y);
        dst[2] = make_float2(re0.z, im0.z); dst[3] = make_float2(re0.w, im0.w);
        dst[4] = make_float2(re1.x, im1.x); dst[5] = make_float2(re1.y, im1.y);
        dst[6] = make_float2(re1.z, im1.z); dst[7] = make_float2(re1.w, im1.w);
    } else {
        *(float4*)&out_zc[(size_t)tok * LAT + j0]     = re0;
        *(float4*)&out_zc[(size_t)tok * LAT + j0 + 4] = re1;
    }
    float l = 0.f;
    l += (re0.x-zr0.x)*(re0.x-zr0.x) + (re0.y-zr0.y)*(re0.y-zr0.y)
       + (re0.z-zr0.z)*(re0.z-zr0.z) + (re0.w-zr0.w)*(re0.w-zr0.w);
    l += (re1.x-zr1.x)*(re1.x-zr1.x) + (re1.y-zr1.y)*(re1.y-zr1.y)
       + (re1.z-zr1.z)*(re1.z-zr1.z) + (re1.w-zr1.w)*(re1.w-zr1.w);
    l += (im0.x-zi0.x)*(im0.x-zi0.x) + (im0.y-zi0.y)*(im0.y-zi0.y)
       + (im0.z-zi0.z)*(im0.z-zi0.z) + (im0.w-zi0.w)*(im0.w-zi0.w);
    l += (im1.x-zi1.x)*(im1.x-zi1.x) + (im1.y-zi1.y)*(im1.y-zi1.y)
       + (im1.z-zi1.z)*(im1.z-zi1.z) + (im1.w-zi1.w)*(im1.w-zi1.w);
#pragma unroll
    for (int m = 32; m; m >>= 1) l += __shfl_xor(l, m, 64);
    if (lane == 0) atomicAdd(out_loss, l);
}

// ---------------- finalize loss ----------------
__global__ void k_fin(float* __restrict__ out_loss) {
    out_loss[0] = out_loss[0] * 1.25f / 33554432.0f;   // *(1+0.25)/(M*KDIM)
}

extern "C" void kernel_launch(void* const* d_in, const int* in_sizes, int n_in,
                              void* d_out, int out_size, void* d_ws, size_t ws_size,
                              hipStream_t stream) {
    const float* z_real     = (const float*)d_in[0];
    const float* z_imag     = (const float*)d_in[1];
    const int*   prev_idx   = (const int*)d_in[2];
    const float* codebook   = (const float*)d_in[3];
    const float* cluster_sz = (const float*)d_in[4];
    const float* embed_avg  = (const float*)d_in[5];
    const float* adjacency  = (const float*)d_in[6];

    float* out = (float*)d_out;

    const size_t REST = 1 + (size_t)M_TOK + (size_t)NSYM * KDIM + NSYM
                      + (size_t)NSYM * KDIM;               // 16,818,177
    size_t zc_n = (size_t)out_size - REST;
    const size_t n_z = (size_t)M_TOK * LAT;
    int interleaved = (zc_n >= 2 * n_z) ? 1 : 0;

    float* out_zc   = out;
    float* out_loss = out + zc_n;
    float* out_idx  = out + zc_n + 1;
    float* out_cb   = out + zc_n + 1 + M_TOK;
    float* out_cs   = out_cb + (size_t)NSYM * KDIM;
    float* out_ea   = out_cs + NSYM;

    // scratch, phase 1 (screen inputs), carved from output regions:
    u16*   A_hi  = (u16*)out_zc;                       // 67.1 MB (zc region)
    u16*   B_hi  = (u16*)out_cb;                       // 16.8 MB (cb region)
    float* cnorm = out_cb + 4194304;                   // 32 KB after B_hi
    float* candV = out_ea;                             // 33.5 MB [256][M] (fills ea region)
    u16*   candI = (u16*)(out_cb + 4202496);           // 8.4 MB  [128][M] (cb free area)

    // scratch, phase 2 (EMA sort), in zc region (A_hi dead after screen; k_zq runs last):
    u32*   counts  = (u32*)out_zc;                     // 32 KB
    u32*   cursors = counts + NSYM;                    // 32 KB
    u32*   offsets = cursors + NSYM;                   // 32 KB
    u32*   list    = offsets + NSYM;                   // 128 KB
    float* scal    = (float*)(list + M_TOK);           // 8 B

    k_convA<<<16384, 256, 0, stream>>>(z_real, z_imag, A_hi);
    k_convB<<<4096, 256, 0, stream>>>(codebook, B_hi, cnorm);
    k_screen<<<1024, 256, 0, stream>>>(A_hi, B_hi, cnorm, candV, candI);
    k_zero<<<32, 256, 0, stream>>>(counts, cursors, out_loss);
    k_select<<<M_TOK / SEL_TOK, 256, 0, stream>>>(z_real, z_imag, prev_idx,
                                                  codebook, adjacency,
                                                  candV, candI, out_idx, counts);
    k_scan<<<1, 1024, 0, stream>>>(counts, cluster_sz, out_cs, offsets, scal);
    k_place<<<M_TOK / 256, 256, 0, stream>>>(out_idx, offsets, cursors, list);
    k_emit<<<NSYM, 256, 0, stream>>>(z_real, z_imag, embed_avg, counts, offsets,
                                     list, out_cs, scal, out_ea, out_cb);
    k_zq<<<M_TOK / 4, 256, 0, stream>>>(z_real, z_imag, codebook, out_idx,
                                        out_zc, out_loss, interleaved);
    k_fin<<<1, 1, 0, stream>>>(out_loss);
}